// Round 1
// baseline (1323.528 us; speedup 1.0000x reference)
//
#include <hip/hip_runtime.h>
#include <cstdint>

#define N_NODES 50000
#define B_SZ 4
#define C_IN 32
#define C_OUT 64
#define K_CHEB 6
#define M_POOL 12500

__global__ void deg_kernel(const int* __restrict__ row, int* __restrict__ deg, int E) {
    int e = blockIdx.x * blockDim.x + threadIdx.x;
    if (e < E) atomicAdd(&deg[row[e]], 1);
}

__global__ void dis_kernel(const int* __restrict__ deg, float* __restrict__ dis, int N) {
    int i = blockIdx.x * blockDim.x + threadIdx.x;
    if (i < N) {
        int d = deg[i];
        dis[i] = d > 0 ? rsqrtf((float)d) : 0.f;
    }
}

__global__ void block_sum_kernel(const int* __restrict__ deg, int* __restrict__ bsum, int N) {
    __shared__ int sm[256];
    int i = blockIdx.x * 256 + threadIdx.x;
    sm[threadIdx.x] = (i < N) ? deg[i] : 0;
    __syncthreads();
    for (int s = 128; s > 0; s >>= 1) {
        if (threadIdx.x < s) sm[threadIdx.x] += sm[threadIdx.x + s];
        __syncthreads();
    }
    if (threadIdx.x == 0) bsum[blockIdx.x] = sm[0];
}

__global__ void scan_bsum_kernel(int* bsum, int nb, int* rowptr, int N, int E) {
    if (blockIdx.x == 0 && threadIdx.x == 0) {
        int run = 0;
        for (int i = 0; i < nb; i++) { int v = bsum[i]; bsum[i] = run; run += v; }
        rowptr[N] = E;
    }
}

__global__ void rowptr_kernel(const int* __restrict__ deg, const int* __restrict__ bsum,
                              int* __restrict__ rowptr, int N) {
    __shared__ int sm[256];
    int i = blockIdx.x * 256 + threadIdx.x;
    sm[threadIdx.x] = (i < N) ? deg[i] : 0;
    __syncthreads();
    if (threadIdx.x == 0) {
        int run = bsum[blockIdx.x];
        for (int t = 0; t < 256; t++) { int v = sm[t]; sm[t] = run; run += v; }
    }
    __syncthreads();
    if (i < N) rowptr[i] = sm[threadIdx.x];
}

__global__ void place_kernel(const int* __restrict__ row, const int* __restrict__ col,
                             const float* __restrict__ dis, const int* __restrict__ rowptr,
                             int* __restrict__ cursor, int* __restrict__ col_s,
                             float* __restrict__ norm_s, int E) {
    int e = blockIdx.x * blockDim.x + threadIdx.x;
    if (e < E) {
        int r = row[e], c = col[e];
        int pos = rowptr[r] + atomicAdd(&cursor[r], 1);
        col_s[pos] = c;
        norm_s[pos] = -dis[r] * dis[c];
    }
}

// out[b,r,c] = alpha * sum_{edges of r} norm * h_prev[b,col,c]  - (prev2 ? prev2[b,r,c] : 0)
__global__ void prop_kernel(const float* __restrict__ h_prev, const float* __restrict__ prev2,
                            float* __restrict__ out,
                            const int* __restrict__ rowptr, const int* __restrict__ col_s,
                            const float* __restrict__ norm_s, float alpha) {
    int r = blockIdx.x * 8 + (threadIdx.x >> 5);
    int c = threadIdx.x & 31;
    int b = blockIdx.y;
    if (r >= N_NODES) return;
    float acc = 0.f;
    int p0 = rowptr[r], p1 = rowptr[r + 1];
    const float* hb = h_prev + (size_t)b * N_NODES * C_IN;
    for (int p = p0; p < p1; ++p) {
        acc += hb[(size_t)col_s[p] * C_IN + c] * norm_s[p];
    }
    size_t idx = ((size_t)b * N_NODES + r) * C_IN + c;
    float v = alpha * acc;
    if (prev2) v -= prev2[idx];
    out[idx] = v;
}

// out_acc[b,n,c] (=|+=) sum_ci Tx[b,n,ci] * W[ci,c]   (+ bias when init)
__global__ void gemm_kernel(const float* __restrict__ Tx, const float* __restrict__ W,
                            const float* __restrict__ bias, float* __restrict__ out_acc,
                            int init) {
    __shared__ float Wl[C_IN * C_OUT];
    __shared__ float txl[4 * C_IN];
    int tid = threadIdx.x;
    for (int i = tid; i < C_IN * C_OUT; i += 256) Wl[i] = W[i];
    int b = blockIdx.y;
    int r0 = blockIdx.x * 4;
    if (tid < 4 * C_IN) {
        int lr = tid >> 5;
        int ci = tid & 31;
        int r = r0 + lr;
        txl[tid] = (r < N_NODES) ? Tx[((size_t)b * N_NODES + r) * C_IN + ci] : 0.f;
    }
    __syncthreads();
    int lr = tid >> 6;
    int c = tid & 63;
    int r = r0 + lr;
    if (r >= N_NODES) return;
    float a = 0.f;
#pragma unroll
    for (int ci = 0; ci < C_IN; ++ci) a += txl[lr * C_IN + ci] * Wl[ci * C_OUT + c];
    size_t idx = ((size_t)b * N_NODES + r) * C_OUT + c;
    if (init) out_acc[idx] = a + bias[c];
    else out_acc[idx] += a;
}

__global__ void pool_kernel(const float* __restrict__ h, const int* __restrict__ prow,
                            const int* __restrict__ pcol, const float* __restrict__ pval,
                            float* __restrict__ out, int P) {
    int pi = blockIdx.x * 4 + (threadIdx.x >> 6);
    int c = threadIdx.x & 63;
    int b = blockIdx.y;
    if (pi >= P) return;
    int r = prow[pi], cl = pcol[pi];
    float v = pval[pi];
    float xv = h[((size_t)b * N_NODES + cl) * C_OUT + c];
    xv = xv > 0.f ? xv : (expf(xv) - 1.f);
    atomicAdd(&out[((size_t)b * M_POOL + r) * C_OUT + c], xv * v);
}

extern "C" void kernel_launch(void* const* d_in, const int* in_sizes, int n_in,
                              void* d_out, int out_size, void* d_ws, size_t ws_size,
                              hipStream_t stream) {
    const float* x    = (const float*)d_in[0];
    const int*   ei   = (const int*)d_in[1];
    const int*   prow = (const int*)d_in[2];
    const int*   pcol = (const int*)d_in[3];
    const float* pval = (const float*)d_in[4];
    const float* W    = (const float*)d_in[5];
    const float* bias = (const float*)d_in[6];
    const int E = in_sizes[1] / 2;
    const int P = in_sizes[2];
    const int N = N_NODES;
    const int* row = ei;
    const int* col = ei + E;

    char* ws = (char*)d_ws;
    size_t o = 0;
    auto alloc = [&](size_t bytes) -> char* {
        char* p = ws + o;
        o += (bytes + 255) & ~(size_t)255;
        return p;
    };
    int nb = (N + 255) / 256;
    int*   deg    = (int*)alloc((size_t)N * 4);
    float* dis    = (float*)alloc((size_t)N * 4);
    int*   rowptr = (int*)alloc((size_t)(N + 1) * 4);
    int*   cursor = (int*)alloc((size_t)N * 4);
    int*   bsum   = (int*)alloc((size_t)nb * 4);
    int*   col_s  = (int*)alloc((size_t)E * 4);
    float* norm_s = (float*)alloc((size_t)E * 4);
    float* TxA    = (float*)alloc((size_t)B_SZ * N * C_IN * 4);
    float* TxB    = (float*)alloc((size_t)B_SZ * N * C_IN * 4);
    float* TxC    = (float*)alloc((size_t)B_SZ * N * C_IN * 4);
    float* outacc = (float*)alloc((size_t)B_SZ * N * C_OUT * 4);

    hipMemsetAsync(d_out, 0, (size_t)out_size * sizeof(float), stream);
    hipMemsetAsync(deg, 0, (size_t)N * 4, stream);
    hipMemsetAsync(cursor, 0, (size_t)N * 4, stream);

    deg_kernel<<<(E + 255) / 256, 256, 0, stream>>>(row, deg, E);
    dis_kernel<<<(N + 255) / 256, 256, 0, stream>>>(deg, dis, N);
    block_sum_kernel<<<nb, 256, 0, stream>>>(deg, bsum, N);
    scan_bsum_kernel<<<1, 64, 0, stream>>>(bsum, nb, rowptr, N, E);
    rowptr_kernel<<<nb, 256, 0, stream>>>(deg, bsum, rowptr, N);
    place_kernel<<<(E + 255) / 256, 256, 0, stream>>>(row, col, dis, rowptr, cursor,
                                                      col_s, norm_s, E);

    dim3 gg((N + 3) / 4, B_SZ);
    dim3 pg((N + 7) / 8, B_SZ);

    // k = 0: out = x @ W0 + bias
    gemm_kernel<<<gg, 256, 0, stream>>>(x, W + 0 * C_IN * C_OUT, bias, outacc, 1);

    // k = 1: Tx1 = prop(x)
    prop_kernel<<<pg, 256, 0, stream>>>(x, nullptr, TxA, rowptr, col_s, norm_s, 1.0f);
    gemm_kernel<<<gg, 256, 0, stream>>>(TxA, W + 1 * C_IN * C_OUT, bias, outacc, 0);

    float* bufs[3] = {TxA, TxB, TxC};
    for (int k = 2; k < K_CHEB; ++k) {
        const float* hp = bufs[(k - 2) % 3];                 // Tx_{k-1}
        const float* p2 = (k == 2) ? x : bufs[(k - 3) % 3];  // Tx_{k-2}
        float* to = bufs[(k - 1) % 3];                       // Tx_k
        prop_kernel<<<pg, 256, 0, stream>>>(hp, p2, to, rowptr, col_s, norm_s, 2.0f);
        gemm_kernel<<<gg, 256, 0, stream>>>(to, W + k * C_IN * C_OUT, bias, outacc, 0);
    }

    // ELU fused into pool gather; scatter-add into zeroed d_out
    dim3 qg((P + 3) / 4, B_SZ);
    pool_kernel<<<qg, 256, 0, stream>>>(outacc, prow, pcol, pval, (float*)d_out, P);
}

// Round 2
// 714.303 us; speedup vs baseline: 1.8529x; 1.8529x over previous
//
#include <hip/hip_runtime.h>
#include <cstdint>

#define N_NODES 50000
#define B_SZ 4
#define C_IN 32
#define C_OUT 64
#define K_CHEB 6
#define M_POOL 12500
#define NS ((size_t)N_NODES * C_IN)
#define G3_ROWS 16

__global__ void deg_kernel(const int* __restrict__ row, int* __restrict__ deg, int E) {
    int e = blockIdx.x * blockDim.x + threadIdx.x;
    if (e < E) atomicAdd(&deg[row[e]], 1);
}

__global__ void dis_kernel(const int* __restrict__ deg, float* __restrict__ dis, int N) {
    int i = blockIdx.x * blockDim.x + threadIdx.x;
    if (i < N) {
        int d = deg[i];
        dis[i] = d > 0 ? rsqrtf((float)d) : 0.f;
    }
}

__global__ void block_sum_kernel(const int* __restrict__ deg, int* __restrict__ bsum, int N) {
    __shared__ int sm[256];
    int i = blockIdx.x * 256 + threadIdx.x;
    sm[threadIdx.x] = (i < N) ? deg[i] : 0;
    __syncthreads();
    for (int s = 128; s > 0; s >>= 1) {
        if (threadIdx.x < s) sm[threadIdx.x] += sm[threadIdx.x + s];
        __syncthreads();
    }
    if (threadIdx.x == 0) bsum[blockIdx.x] = sm[0];
}

__global__ void scan_bsum_kernel(int* bsum, int nb, int* rowptr, int N, int E) {
    if (blockIdx.x == 0 && threadIdx.x == 0) {
        int run = 0;
        for (int i = 0; i < nb; i++) { int v = bsum[i]; bsum[i] = run; run += v; }
        rowptr[N] = E;
    }
}

__global__ void rowptr_kernel(const int* __restrict__ deg, const int* __restrict__ bsum,
                              int* __restrict__ rowptr, int N) {
    __shared__ int sm[256];
    int i = blockIdx.x * 256 + threadIdx.x;
    sm[threadIdx.x] = (i < N) ? deg[i] : 0;
    __syncthreads();
    if (threadIdx.x == 0) {
        int run = bsum[blockIdx.x];
        for (int t = 0; t < 256; t++) { int v = sm[t]; sm[t] = run; run += v; }
    }
    __syncthreads();
    if (i < N) rowptr[i] = sm[threadIdx.x];
}

__global__ void place_kernel(const int* __restrict__ row, const int* __restrict__ col,
                             const float* __restrict__ dis, const int* __restrict__ rowptr,
                             int* __restrict__ cursor, int* __restrict__ col_s,
                             float* __restrict__ norm_s, int E) {
    int e = blockIdx.x * blockDim.x + threadIdx.x;
    if (e < E) {
        int r = row[e], c = col[e];
        int pos = rowptr[r] + atomicAdd(&cursor[r], 1);
        col_s[pos] = c;
        norm_s[pos] = -dis[r] * dis[c];
    }
}

// All 4 batches per thread: out[b,r,c] = alpha * sum norm * h[b,col,c] - (p2 ? p2[b,r,c] : 0)
__global__ void prop_kernel(const float* __restrict__ hp, const float* __restrict__ p2,
                            float* __restrict__ out,
                            const int* __restrict__ rowptr, const int* __restrict__ col_s,
                            const float* __restrict__ norm_s, float alpha) {
    int r = blockIdx.x * 8 + (threadIdx.x >> 5);
    int c = threadIdx.x & 31;
    if (r >= N_NODES) return;
    float a0 = 0.f, a1 = 0.f, a2 = 0.f, a3 = 0.f;
    int p0 = rowptr[r], p1 = rowptr[r + 1];
    int p = p0;
    for (; p + 1 < p1; p += 2) {
        int cl0 = col_s[p], cl1 = col_s[p + 1];
        float n0 = norm_s[p], n1 = norm_s[p + 1];
        const float* b0 = hp + (size_t)cl0 * C_IN + c;
        const float* b1 = hp + (size_t)cl1 * C_IN + c;
        float v00 = b0[0], v01 = b0[NS], v02 = b0[2 * NS], v03 = b0[3 * NS];
        float v10 = b1[0], v11 = b1[NS], v12 = b1[2 * NS], v13 = b1[3 * NS];
        a0 += v00 * n0 + v10 * n1;
        a1 += v01 * n0 + v11 * n1;
        a2 += v02 * n0 + v12 * n1;
        a3 += v03 * n0 + v13 * n1;
    }
    if (p < p1) {
        int cl0 = col_s[p];
        float n0 = norm_s[p];
        const float* b0 = hp + (size_t)cl0 * C_IN + c;
        a0 += b0[0] * n0;
        a1 += b0[NS] * n0;
        a2 += b0[2 * NS] * n0;
        a3 += b0[3 * NS] * n0;
    }
    size_t idx = (size_t)r * C_IN + c;
    if (p2) {
        out[idx]          = alpha * a0 - p2[idx];
        out[idx + NS]     = alpha * a1 - p2[idx + NS];
        out[idx + 2 * NS] = alpha * a2 - p2[idx + 2 * NS];
        out[idx + 3 * NS] = alpha * a3 - p2[idx + 3 * NS];
    } else {
        out[idx]          = alpha * a0;
        out[idx + NS]     = alpha * a1;
        out[idx + 2 * NS] = alpha * a2;
        out[idx + 3 * NS] = alpha * a3;
    }
}

// outacc[b,n,c] (=|+=) sum over 3 sources s: T_s[b,n,:] @ W[s]  (+bias when init)
__global__ void gemm3_kernel(const float* __restrict__ T0, const float* __restrict__ T1,
                             const float* __restrict__ T2, const float* __restrict__ W,
                             const float* __restrict__ bias, float* __restrict__ outacc,
                             int init) {
    __shared__ float Wl[3 * C_IN * C_OUT];    // 24 KB
    __shared__ float txl[3 * G3_ROWS * C_IN]; // 6 KB
    int tid = threadIdx.x;
    for (int i = tid; i < 3 * C_IN * C_OUT; i += 256) Wl[i] = W[i];
    int b = blockIdx.y;
    int r0 = blockIdx.x * G3_ROWS;
    const float* Ts[3] = {T0, T1, T2};
    for (int i = tid; i < 3 * G3_ROWS * C_IN; i += 256) {
        int s = i / (G3_ROWS * C_IN);
        int rem = i - s * (G3_ROWS * C_IN);
        int rr = rem >> 5;
        int ci = rem & 31;
        int r = r0 + rr;
        txl[i] = (r < N_NODES) ? Ts[s][((size_t)b * N_NODES + r) * C_IN + ci] : 0.f;
    }
    __syncthreads();
    int lr = tid >> 6;
    int c = tid & 63;
    float bv = bias[c];
#pragma unroll
    for (int i = 0; i < G3_ROWS / 4; i++) {
        int rr = lr + 4 * i;
        int r = r0 + rr;
        if (r >= N_NODES) continue;
        float a = init ? bv : 0.f;
#pragma unroll
        for (int s = 0; s < 3; s++)
#pragma unroll
            for (int ci = 0; ci < C_IN; ci++)
                a += txl[(s * G3_ROWS + rr) * C_IN + ci] * Wl[(s * C_IN + ci) * C_OUT + c];
        size_t idx = ((size_t)b * N_NODES + r) * C_OUT + c;
        if (init) outacc[idx] = a;
        else outacc[idx] += a;
    }
}

__global__ void pool_kernel(const float* __restrict__ h, const int* __restrict__ prow,
                            const int* __restrict__ pcol, const float* __restrict__ pval,
                            float* __restrict__ out, int P) {
    int pi = blockIdx.x * 4 + (threadIdx.x >> 6);
    int c = threadIdx.x & 63;
    int b = blockIdx.y;
    if (pi >= P) return;
    int r = prow[pi], cl = pcol[pi];
    float v = pval[pi];
    float xv = h[((size_t)b * N_NODES + cl) * C_OUT + c];
    xv = xv > 0.f ? xv : (expf(xv) - 1.f);
    atomicAdd(&out[((size_t)b * M_POOL + r) * C_OUT + c], xv * v);
}

extern "C" void kernel_launch(void* const* d_in, const int* in_sizes, int n_in,
                              void* d_out, int out_size, void* d_ws, size_t ws_size,
                              hipStream_t stream) {
    const float* x    = (const float*)d_in[0];
    const int*   ei   = (const int*)d_in[1];
    const int*   prow = (const int*)d_in[2];
    const int*   pcol = (const int*)d_in[3];
    const float* pval = (const float*)d_in[4];
    const float* W    = (const float*)d_in[5];
    const float* bias = (const float*)d_in[6];
    const int E = in_sizes[1] / 2;
    const int P = in_sizes[2];
    const int N = N_NODES;
    const int* row = ei;
    const int* col = ei + E;

    char* ws = (char*)d_ws;
    size_t o = 0;
    auto alloc = [&](size_t bytes) -> char* {
        char* p = ws + o;
        o += (bytes + 255) & ~(size_t)255;
        return p;
    };
    int nb = (N + 255) / 256;
    int*   deg    = (int*)alloc((size_t)N * 4);
    float* dis    = (float*)alloc((size_t)N * 4);
    int*   rowptr = (int*)alloc((size_t)(N + 1) * 4);
    int*   cursor = (int*)alloc((size_t)N * 4);
    int*   bsum   = (int*)alloc((size_t)nb * 4);
    int*   col_s  = (int*)alloc((size_t)E * 4);
    float* norm_s = (float*)alloc((size_t)E * 4);
    float* bufA   = (float*)alloc((size_t)B_SZ * N * C_IN * 4);
    float* bufB   = (float*)alloc((size_t)B_SZ * N * C_IN * 4);
    float* bufC   = (float*)alloc((size_t)B_SZ * N * C_IN * 4);
    float* outacc = (float*)alloc((size_t)B_SZ * N * C_OUT * 4);

    hipMemsetAsync(d_out, 0, (size_t)out_size * sizeof(float), stream);
    hipMemsetAsync(deg, 0, (size_t)N * 4, stream);
    hipMemsetAsync(cursor, 0, (size_t)N * 4, stream);

    deg_kernel<<<(E + 255) / 256, 256, 0, stream>>>(row, deg, E);
    dis_kernel<<<(N + 255) / 256, 256, 0, stream>>>(deg, dis, N);
    block_sum_kernel<<<nb, 256, 0, stream>>>(deg, bsum, N);
    scan_bsum_kernel<<<1, 64, 0, stream>>>(bsum, nb, rowptr, N, E);
    rowptr_kernel<<<nb, 256, 0, stream>>>(deg, bsum, rowptr, N);
    place_kernel<<<(E + 255) / 256, 256, 0, stream>>>(row, col, dis, rowptr, cursor,
                                                      col_s, norm_s, E);

    dim3 pg((N + 7) / 8, 1);
    dim3 gg(N / G3_ROWS, B_SZ);   // 50000 % 16 == 0? 50000/16=3125 exactly
    dim3 qg((P + 3) / 4, B_SZ);

    // T1 = prop(x); T2 = 2*prop(T1) - x
    prop_kernel<<<pg, 256, 0, stream>>>(x, nullptr, bufA, rowptr, col_s, norm_s, 1.0f);
    prop_kernel<<<pg, 256, 0, stream>>>(bufA, x, bufB, rowptr, col_s, norm_s, 2.0f);
    // out = [x,T1,T2] @ W[0:3] + bias
    gemm3_kernel<<<gg, 256, 0, stream>>>(x, bufA, bufB, W, bias, outacc, 1);
    // T3 = 2*prop(T2) - T1 ; T4 = 2*prop(T3) - T2 ; T5 = 2*prop(T4) - T3
    prop_kernel<<<pg, 256, 0, stream>>>(bufB, bufA, bufC, rowptr, col_s, norm_s, 2.0f);
    prop_kernel<<<pg, 256, 0, stream>>>(bufC, bufB, bufA, rowptr, col_s, norm_s, 2.0f);
    prop_kernel<<<pg, 256, 0, stream>>>(bufA, bufC, bufB, rowptr, col_s, norm_s, 2.0f);
    // out += [T3,T4,T5] @ W[3:6]
    gemm3_kernel<<<gg, 256, 0, stream>>>(bufC, bufA, bufB, W + 3 * C_IN * C_OUT, bias, outacc, 0);

    // ELU fused into pool gather; scatter-add into zeroed d_out
    pool_kernel<<<qg, 256, 0, stream>>>(outacc, prow, pcol, pval, (float*)d_out, P);
}

// Round 3
// 528.614 us; speedup vs baseline: 2.5038x; 1.3513x over previous
//
#include <hip/hip_runtime.h>
#include <cstdint>

#define N_NODES 50000
#define B_SZ 4
#define C_IN 32
#define C_OUT 64
#define K_CHEB 6
#define M_POOL 12500
#define NS ((size_t)N_NODES * C_IN)
#define ZS ((size_t)N_NODES * C_OUT)

typedef __bf16 bf16x8 __attribute__((ext_vector_type(8)));
typedef unsigned short us8 __attribute__((ext_vector_type(8)));
typedef float f32x4 __attribute__((ext_vector_type(4)));

__device__ __forceinline__ unsigned short f2bf(float f) {
    union { float f; unsigned int u; } v;
    v.f = f;
    unsigned int r = v.u + 0x7fffu + ((v.u >> 16) & 1u);
    return (unsigned short)(r >> 16);
}

// ---------------- CSR build (generic over row count) ----------------
__global__ void deg_kernel(const int* __restrict__ row, int* __restrict__ deg, int E) {
    int e = blockIdx.x * blockDim.x + threadIdx.x;
    if (e < E) atomicAdd(&deg[row[e]], 1);
}

__global__ void dis_kernel(const int* __restrict__ deg, float* __restrict__ dis, int N) {
    int i = blockIdx.x * blockDim.x + threadIdx.x;
    if (i < N) {
        int d = deg[i];
        dis[i] = d > 0 ? rsqrtf((float)d) : 0.f;
    }
}

__global__ void block_sum_kernel(const int* __restrict__ deg, int* __restrict__ bsum, int N) {
    __shared__ int sm[256];
    int i = blockIdx.x * 256 + threadIdx.x;
    sm[threadIdx.x] = (i < N) ? deg[i] : 0;
    __syncthreads();
    for (int s = 128; s > 0; s >>= 1) {
        if (threadIdx.x < s) sm[threadIdx.x] += sm[threadIdx.x + s];
        __syncthreads();
    }
    if (threadIdx.x == 0) bsum[blockIdx.x] = sm[0];
}

__global__ void scan_bsum_kernel(int* bsum, int nb, int* rowptr, int N, int E) {
    if (blockIdx.x == 0 && threadIdx.x == 0) {
        int run = 0;
        for (int i = 0; i < nb; i++) { int v = bsum[i]; bsum[i] = run; run += v; }
        rowptr[N] = E;
    }
}

__global__ void rowptr_kernel(const int* __restrict__ deg, const int* __restrict__ bsum,
                              int* __restrict__ rowptr, int N) {
    __shared__ int sm[256];
    int i = blockIdx.x * 256 + threadIdx.x;
    sm[threadIdx.x] = (i < N) ? deg[i] : 0;
    __syncthreads();
    if (threadIdx.x == 0) {
        int run = bsum[blockIdx.x];
        for (int t = 0; t < 256; t++) { int v = sm[t]; sm[t] = run; run += v; }
    }
    __syncthreads();
    if (i < N) rowptr[i] = sm[threadIdx.x];
}

__global__ void place_kernel(const int* __restrict__ row, const int* __restrict__ col,
                             const float* __restrict__ dis, const int* __restrict__ rowptr,
                             int* __restrict__ cursor, int* __restrict__ col_s,
                             float* __restrict__ norm_s, int E) {
    int e = blockIdx.x * blockDim.x + threadIdx.x;
    if (e < E) {
        int r = row[e], c = col[e];
        int pos = rowptr[r] + atomicAdd(&cursor[r], 1);
        col_s[pos] = c;
        norm_s[pos] = -dis[r] * dis[c];
    }
}

__global__ void place2_kernel(const int* __restrict__ prow, const int* __restrict__ pcol,
                              const float* __restrict__ pval, const int* __restrict__ rowptr,
                              int* __restrict__ cursor, int* __restrict__ col_s,
                              float* __restrict__ val_s, int P) {
    int e = blockIdx.x * blockDim.x + threadIdx.x;
    if (e < P) {
        int r = prow[e];
        int pos = rowptr[r] + atomicAdd(&cursor[r], 1);
        col_s[pos] = pcol[e];
        val_s[pos] = pval[e];
    }
}

// ---------------- Chebyshev propagation (all 4 batches per thread) ----------------
__global__ void prop_kernel(const float* __restrict__ hp, const float* __restrict__ p2,
                            float* __restrict__ out,
                            const int* __restrict__ rowptr, const int* __restrict__ col_s,
                            const float* __restrict__ norm_s, float alpha) {
    int r = blockIdx.x * 8 + (threadIdx.x >> 5);
    int c = threadIdx.x & 31;
    if (r >= N_NODES) return;
    float a0 = 0.f, a1 = 0.f, a2 = 0.f, a3 = 0.f;
    int p0 = rowptr[r], p1 = rowptr[r + 1];
    int p = p0;
    for (; p + 3 < p1; p += 4) {
        int cl0 = col_s[p], cl1 = col_s[p + 1], cl2 = col_s[p + 2], cl3 = col_s[p + 3];
        float n0 = norm_s[p], n1 = norm_s[p + 1], n2 = norm_s[p + 2], n3 = norm_s[p + 3];
        const float* b0 = hp + (size_t)cl0 * C_IN + c;
        const float* b1 = hp + (size_t)cl1 * C_IN + c;
        const float* b2 = hp + (size_t)cl2 * C_IN + c;
        const float* b3 = hp + (size_t)cl3 * C_IN + c;
        a0 += b0[0] * n0 + b1[0] * n1 + b2[0] * n2 + b3[0] * n3;
        a1 += b0[NS] * n0 + b1[NS] * n1 + b2[NS] * n2 + b3[NS] * n3;
        a2 += b0[2 * NS] * n0 + b1[2 * NS] * n1 + b2[2 * NS] * n2 + b3[2 * NS] * n3;
        a3 += b0[3 * NS] * n0 + b1[3 * NS] * n1 + b2[3 * NS] * n2 + b3[3 * NS] * n3;
    }
    for (; p < p1; ++p) {
        int cl0 = col_s[p];
        float n0 = norm_s[p];
        const float* b0 = hp + (size_t)cl0 * C_IN + c;
        a0 += b0[0] * n0;
        a1 += b0[NS] * n0;
        a2 += b0[2 * NS] * n0;
        a3 += b0[3 * NS] * n0;
    }
    size_t idx = (size_t)r * C_IN + c;
    if (p2) {
        out[idx]          = alpha * a0 - p2[idx];
        out[idx + NS]     = alpha * a1 - p2[idx + NS];
        out[idx + 2 * NS] = alpha * a2 - p2[idx + 2 * NS];
        out[idx + 3 * NS] = alpha * a3 - p2[idx + 3 * NS];
    } else {
        out[idx]          = alpha * a0;
        out[idx + NS]     = alpha * a1;
        out[idx + 2 * NS] = alpha * a2;
        out[idx + 3 * NS] = alpha * a3;
    }
}

// ---------------- W pack: [s][t][lane][j] in bf16 fragment order ----------------
__global__ void packW_kernel(const float* __restrict__ W, unsigned short* __restrict__ Wp) {
    int i = blockIdx.x * 256 + threadIdx.x;
    if (i >= K_CHEB * 4 * 64 * 8) return;
    int j = i & 7;
    int lane = (i >> 3) & 63;
    int t = (i >> 9) & 3;
    int s = i >> 11;
    int k = (lane >> 4) * 8 + j;
    int col = t * 16 + (lane & 15);
    Wp[i] = f2bf(W[((size_t)s * C_IN + k) * C_OUT + col]);
}

// ---------------- Fused 3-source MFMA GEMM ----------------
// z[g, 0:64] (=|+=) sum_s Ts[g, 0:32] @ W[s]; pass1 adds bias, pass2 adds z and applies ELU
__global__ void gemm_mfma_kernel(const float* __restrict__ T0, const float* __restrict__ T1,
                                 const float* __restrict__ T2,
                                 const unsigned short* __restrict__ Wp,
                                 const float* __restrict__ bias, float* __restrict__ z,
                                 int second) {
    int lane = threadIdx.x & 63;
    int wave = (blockIdx.x << 2) + (threadIdx.x >> 6);
    int r0 = wave << 4;  // 16 rows per wave; 200000/16 = 12500 waves
    int ga = r0 + (lane & 15);
    int koff = (lane >> 4) * 8;
    const float* Ts[3] = {T0, T1, T2};

    bf16x8 afr[3];
#pragma unroll
    for (int s = 0; s < 3; s++) {
        const float4* s4 = (const float4*)(Ts[s] + (size_t)ga * C_IN + koff);
        float4 lo = s4[0], hi = s4[1];
        us8 au;
        au[0] = f2bf(lo.x); au[1] = f2bf(lo.y); au[2] = f2bf(lo.z); au[3] = f2bf(lo.w);
        au[4] = f2bf(hi.x); au[5] = f2bf(hi.y); au[6] = f2bf(hi.z); au[7] = f2bf(hi.w);
        afr[s] = __builtin_bit_cast(bf16x8, au);
    }

    int orow = r0 + ((lane >> 4) << 2);
#pragma unroll
    for (int t = 0; t < 4; t++) {
        f32x4 acc = {0.f, 0.f, 0.f, 0.f};
#pragma unroll
        for (int s = 0; s < 3; s++) {
            bf16x8 b = *(const bf16x8*)(Wp + (((s << 2) + t) * 64 + lane) * 8);
            acc = __builtin_amdgcn_mfma_f32_16x16x32_bf16(afr[s], b, acc, 0, 0, 0);
        }
        int col = (t << 4) + (lane & 15);
        float bv = bias[col];
#pragma unroll
        for (int rg = 0; rg < 4; rg++) {
            size_t idx = (size_t)(orow + rg) * C_OUT + col;
            float v = acc[rg];
            if (!second) {
                z[idx] = v + bv;
            } else {
                v += z[idx];
                z[idx] = v > 0.f ? v : (expf(v) - 1.f);
            }
        }
    }
}

// ---------------- Pool: CSR gather-reduce (no atomics) ----------------
__global__ void pool_csr_kernel(const float* __restrict__ z, const int* __restrict__ rowptr,
                                const int* __restrict__ col_s, const float* __restrict__ val_s,
                                float* __restrict__ out) {
    int r = blockIdx.x * 4 + (threadIdx.x >> 6);
    int c = threadIdx.x & 63;
    if (r >= M_POOL) return;
    float a0 = 0.f, a1 = 0.f, a2 = 0.f, a3 = 0.f;
    int p0 = rowptr[r], p1 = rowptr[r + 1];
    for (int p = p0; p < p1; ++p) {
        int cl = col_s[p];
        float v = val_s[p];
        const float* zb = z + (size_t)cl * C_OUT + c;
        a0 += zb[0] * v;
        a1 += zb[ZS] * v;
        a2 += zb[2 * ZS] * v;
        a3 += zb[3 * ZS] * v;
    }
    size_t idx = (size_t)r * C_OUT + c;
    out[idx]                       = a0;
    out[idx + (size_t)M_POOL * 64] = a1;
    out[idx + 2 * (size_t)M_POOL * 64] = a2;
    out[idx + 3 * (size_t)M_POOL * 64] = a3;
}

extern "C" void kernel_launch(void* const* d_in, const int* in_sizes, int n_in,
                              void* d_out, int out_size, void* d_ws, size_t ws_size,
                              hipStream_t stream) {
    const float* x    = (const float*)d_in[0];
    const int*   ei   = (const int*)d_in[1];
    const int*   prow = (const int*)d_in[2];
    const int*   pcol = (const int*)d_in[3];
    const float* pval = (const float*)d_in[4];
    const float* W    = (const float*)d_in[5];
    const float* bias = (const float*)d_in[6];
    const int E = in_sizes[1] / 2;
    const int P = in_sizes[2];
    const int N = N_NODES;
    const int* row = ei;
    const int* col = ei + E;

    char* ws = (char*)d_ws;
    size_t o = 0;
    auto alloc = [&](size_t bytes) -> char* {
        char* p = ws + o;
        o += (bytes + 255) & ~(size_t)255;
        return p;
    };
    int nb  = (N + 255) / 256;
    int nb2 = (M_POOL + 255) / 256;
    int*   deg     = (int*)alloc((size_t)N * 4);
    float* dis     = (float*)alloc((size_t)N * 4);
    int*   rowptr  = (int*)alloc((size_t)(N + 1) * 4);
    int*   cursor  = (int*)alloc((size_t)N * 4);
    int*   bsum    = (int*)alloc((size_t)nb * 4);
    int*   col_s   = (int*)alloc((size_t)E * 4);
    float* norm_s  = (float*)alloc((size_t)E * 4);
    int*   deg2    = (int*)alloc((size_t)M_POOL * 4);
    int*   rowptr2 = (int*)alloc((size_t)(M_POOL + 1) * 4);
    int*   cursor2 = (int*)alloc((size_t)M_POOL * 4);
    int*   pcol_s  = (int*)alloc((size_t)P * 4);
    float* pval_s  = (float*)alloc((size_t)P * 4);
    unsigned short* Wp = (unsigned short*)alloc((size_t)K_CHEB * 4 * 64 * 8 * 2);
    float* bufA    = (float*)alloc((size_t)B_SZ * N * C_IN * 4);
    float* bufB    = (float*)alloc((size_t)B_SZ * N * C_IN * 4);
    float* bufC    = (float*)alloc((size_t)B_SZ * N * C_IN * 4);
    float* z       = (float*)alloc((size_t)B_SZ * N * C_OUT * 4);

    hipMemsetAsync(deg, 0, (size_t)N * 4, stream);
    hipMemsetAsync(cursor, 0, (size_t)N * 4, stream);
    hipMemsetAsync(deg2, 0, (size_t)M_POOL * 4, stream);
    hipMemsetAsync(cursor2, 0, (size_t)M_POOL * 4, stream);

    // main CSR
    deg_kernel<<<(E + 255) / 256, 256, 0, stream>>>(row, deg, E);
    dis_kernel<<<(N + 255) / 256, 256, 0, stream>>>(deg, dis, N);
    block_sum_kernel<<<nb, 256, 0, stream>>>(deg, bsum, N);
    scan_bsum_kernel<<<1, 64, 0, stream>>>(bsum, nb, rowptr, N, E);
    rowptr_kernel<<<nb, 256, 0, stream>>>(deg, bsum, rowptr, N);
    place_kernel<<<(E + 255) / 256, 256, 0, stream>>>(row, col, dis, rowptr, cursor,
                                                      col_s, norm_s, E);
    // pool CSR (reuses bsum scratch)
    deg_kernel<<<(P + 255) / 256, 256, 0, stream>>>(prow, deg2, P);
    block_sum_kernel<<<nb2, 256, 0, stream>>>(deg2, bsum, M_POOL);
    scan_bsum_kernel<<<1, 64, 0, stream>>>(bsum, nb2, rowptr2, M_POOL, P);
    rowptr_kernel<<<nb2, 256, 0, stream>>>(deg2, bsum, rowptr2, M_POOL);
    place2_kernel<<<(P + 255) / 256, 256, 0, stream>>>(prow, pcol, pval, rowptr2, cursor2,
                                                       pcol_s, pval_s, P);
    // W pack
    packW_kernel<<<(K_CHEB * 4 * 64 * 8 + 255) / 256, 256, 0, stream>>>(W, Wp);

    dim3 pg((N + 7) / 8, 1);
    int gemm_blocks = (B_SZ * N) / 64;  // 200000/64 = 3125

    // T1 = prop(x); T2 = 2*prop(T1) - x
    prop_kernel<<<pg, 256, 0, stream>>>(x, nullptr, bufA, rowptr, col_s, norm_s, 1.0f);
    prop_kernel<<<pg, 256, 0, stream>>>(bufA, x, bufB, rowptr, col_s, norm_s, 2.0f);
    // z = [x,T1,T2] @ W[0:3] + bias
    gemm_mfma_kernel<<<gemm_blocks, 256, 0, stream>>>(x, bufA, bufB, Wp, bias, z, 0);
    // T3, T4, T5
    prop_kernel<<<pg, 256, 0, stream>>>(bufB, bufA, bufC, rowptr, col_s, norm_s, 2.0f);
    prop_kernel<<<pg, 256, 0, stream>>>(bufC, bufB, bufA, rowptr, col_s, norm_s, 2.0f);
    prop_kernel<<<pg, 256, 0, stream>>>(bufA, bufC, bufB, rowptr, col_s, norm_s, 2.0f);
    // z = ELU(z + [T3,T4,T5] @ W[3:6])
    gemm_mfma_kernel<<<gemm_blocks, 256, 0, stream>>>(bufC, bufA, bufB, Wp + 3 * 4 * 64 * 8,
                                                      bias, z, 1);
    // pool (deterministic CSR reduce)
    pool_csr_kernel<<<(M_POOL + 3) / 4, 256, 0, stream>>>(z, rowptr2, pcol_s, pval_s,
                                                          (float*)d_out);
}